// Round 10
// baseline (348.630 us; speedup 1.0000x reference)
//
#include <hip/hip_runtime.h>

#define N_NODES 100000
#define N_EDGES 1600000
#define D_IN 128
#define D_HID 64

#define BKT_SHIFT 8
#define BKT_NODES 256
#define NB 391          // ceil(N_NODES / 256) buckets
#define BKT_CAP 5120    // per-bucket srcs capacity (mean 4096, +16 sigma)

#define HIST_NB 392     // hist-role blocks in fused kernel
#define GEMM_NB 782     // gemm-role blocks (2 tiles of 64 nodes each)
#define FST 512

typedef __attribute__((ext_vector_type(8))) short bf16x8;
typedef __attribute__((ext_vector_type(4))) float f32x4;

__device__ __forceinline__ unsigned short f2b(float f) {
    union { float f; unsigned u; } c; c.f = f;
    unsigned r = (c.u + 0x7FFFu + ((c.u >> 16) & 1u)) >> 16;   // RNE
    return (unsigned short)r;
}
__device__ __forceinline__ float blo(unsigned u) { return __uint_as_float(u << 16); }
__device__ __forceinline__ float bhi(unsigned u) { return __uint_as_float(u & 0xffff0000u); }

// ===== fused: blocks [0,392) = degree histogram; blocks [392,1174) = layer-1 GEMM ===
// h1s written UNSCALED (dis applied per-edge in gather1) -> no hist->gemm dependency.
#define LS 136
__global__ __launch_bounds__(FST) void k_fused(const int* __restrict__ dst,
                                               int* __restrict__ deg, int E,
                                               const float* __restrict__ x,
                                               const float* __restrict__ W1,
                                               unsigned short* __restrict__ h1s, int n) {
    __shared__ __align__(16) unsigned char smem[52224];
    int tid = threadIdx.x;

    if (blockIdx.x < HIST_NB) {
        // ---------------- degree histogram role ----------------
        int stride = HIST_NB * FST;
        for (int e = blockIdx.x * FST + tid; e < E; e += stride)
            atomicAdd(&deg[dst[e]], 1);
    } else {
        // ---------------- GEMM role: 2 independent 64-node tiles ----------------
        unsigned short* ws = (unsigned short*)smem;        // [64][LS] shared W1^T
        unsigned short* xs = ws + 64 * LS;                 // 2 x [64][LS]
        int half = tid >> 8;          // 0/1 (waves 0-3 / 4-7)
        int t2 = tid & 255;
        int node0 = (blockIdx.x - HIST_NB) * 128 + half * 64;
        unsigned short* xsh = xs + half * 64 * LS;

        // W1 [128][64] fp32 (L2-hot) -> ws[f][k] bf16, cooperative across 512 thr
#pragma unroll
        for (int it = 0; it < 16; ++it) {
            int e = tid + it * 512;
            int k = e >> 6, f = e & 63;
            ws[f * LS + k] = f2b(W1[e]);
        }
#pragma unroll
        for (int it = 0; it < 8; ++it) {
            int e4 = t2 + it * 256;
            int node = e4 >> 5;
            int k = (e4 & 31) * 4;
            float4 v = make_float4(0.f, 0.f, 0.f, 0.f);
            if (node0 + node < n)
                v = ((const float4*)x)[((size_t)(node0 + node) * D_IN + k) >> 2];
            uint2 u;
            u.x = (unsigned)f2b(v.x) | ((unsigned)f2b(v.y) << 16);
            u.y = (unsigned)f2b(v.z) | ((unsigned)f2b(v.w) << 16);
            *(uint2*)&xsh[node * LS + k] = u;
        }
        __syncthreads();

        int wv = t2 >> 6;
        int lane = t2 & 63;
        int m16 = lane & 15;
        int q = lane >> 4;

        bf16x8 afrag[4];
#pragma unroll
        for (int ks = 0; ks < 4; ++ks)
            afrag[ks] = *(const bf16x8*)&xsh[(wv * 16 + m16) * LS + ks * 32 + q * 8];

        f32x4 acc[4];
#pragma unroll
        for (int ft = 0; ft < 4; ++ft) acc[ft] = (f32x4){0.f, 0.f, 0.f, 0.f};

#pragma unroll
        for (int ft = 0; ft < 4; ++ft)
#pragma unroll
            for (int ks = 0; ks < 4; ++ks) {
                bf16x8 bfrag = *(const bf16x8*)&ws[(ft * 16 + m16) * LS + ks * 32 + q * 8];
                acc[ft] = __builtin_amdgcn_mfma_f32_16x16x32_bf16(afrag[ks], bfrag, acc[ft], 0, 0, 0);
            }

        // unscaled h1s; 32B-sector-aligned stores (16 lanes x 2B contiguous)
#pragma unroll
        for (int r = 0; r < 4; ++r) {
            int node = node0 + wv * 16 + q * 4 + r;
            if (node < n) {
#pragma unroll
                for (int ft = 0; ft < 4; ++ft)
                    h1s[(size_t)node * D_HID + ft * 16 + m16] = f2b(acc[ft][r]);
            }
        }
    }
}

// ===== rows: per-bucket exclusive scan of deg -> row_start/row_end/cursor/dis ======
__global__ __launch_bounds__(256) void k_rows(const int* __restrict__ deg,
                                              int* __restrict__ row_start,
                                              int* __restrict__ row_end,
                                              int* __restrict__ cursor,
                                              float* __restrict__ dis, int n) {
    __shared__ int cnt[BKT_NODES];
    __shared__ int exc[BKT_NODES];
    int b = blockIdx.x;
    int tid = threadIdx.x;
    int node = (b << BKT_SHIFT) + tid;
    int d = (node < n) ? deg[node] : 0;
    cnt[tid] = d;
    __syncthreads();

    if (tid < 64) {   // wave-0 exclusive scan of cnt[256]
        int run = 0;
        for (int c = 0; c < BKT_NODES; c += 64) {
            int v = cnt[c + tid];
            int inc = v;
            for (int off = 1; off < 64; off <<= 1) {
                int t2 = __shfl_up(inc, off);
                if (tid >= off) inc += t2;
            }
            exc[c + tid] = run + inc - v;
            run += __shfl(inc, 63);
        }
    }
    __syncthreads();

    if (node < n) {
        int rs = b * BKT_CAP + exc[tid];
        row_start[node] = rs;
        row_end[node] = rs + d;
        cursor[node] = rs;
        dis[node] = rsqrtf((float)d + 1.0f);
    }
}

// ===== scatter: direct CSR fill via per-node global cursors =====
__global__ __launch_bounds__(256) void k_scatter(const int* __restrict__ src,
                                                 const int* __restrict__ dst,
                                                 int* __restrict__ cursor,
                                                 int* __restrict__ srcs_sorted, int E) {
    int stride = gridDim.x * 256;
    for (int e = blockIdx.x * 256 + threadIdx.x; e < E; e += stride) {
        int d = dst[e], s = src[e];
        int p = atomicAdd(&cursor[d], 1);
        srcs_sorted[p] = s;
    }
}

// ================= fused agg1 + bias + ReLU + dot(W2) -> zd = z*dis =================
// Half-wave per node, 4 edge groups x 8 feat lanes; 4-deep load batching.
// h1s is UNSCALED -> apply dis[src] per edge (coalesced 4B request alongside row load).
__global__ __launch_bounds__(256) void k_gather1(const int* __restrict__ srcs,
                                                 const int* __restrict__ row_start,
                                                 const int* __restrict__ row_end,
                                                 const float* __restrict__ dis,
                                                 const uint4* __restrict__ h4,
                                                 const float* __restrict__ b1,
                                                 const float* __restrict__ W2,
                                                 float* __restrict__ zd, int n) {
    int i = blockIdx.x * 8 + (threadIdx.x >> 5);     // node for this half-wave
    int lane = threadIdx.x & 63;
    int g = (lane >> 3) & 3;  // edge group within half-wave
    int m8 = lane & 7;        // feature block (feats 8*m8 .. 8*m8+7)
    float dd = dis[i];

    float a0, a1, a2, a3, a4, a5, a6, a7;
    {   // self-loop handled by group 0: contributes dis_i * h_i
        uint4 u = h4[(unsigned)i * 8u + m8];
        float w = (g == 0) ? dd : 0.f;
        a0 = w * blo(u.x); a1 = w * bhi(u.x);
        a2 = w * blo(u.y); a3 = w * bhi(u.y);
        a4 = w * blo(u.z); a5 = w * bhi(u.z);
        a6 = w * blo(u.w); a7 = w * bhi(u.w);
    }

#define ACC(u, ds) { a0 = fmaf(ds, blo(u.x), a0); a1 = fmaf(ds, bhi(u.x), a1); \
                     a2 = fmaf(ds, blo(u.y), a2); a3 = fmaf(ds, bhi(u.y), a3); \
                     a4 = fmaf(ds, blo(u.z), a4); a5 = fmaf(ds, bhi(u.z), a5); \
                     a6 = fmaf(ds, blo(u.w), a6); a7 = fmaf(ds, bhi(u.w), a7); }
    int end = row_end[i];
    int j = row_start[i] + g;
    for (; j + 12 < end; j += 16) {             // 4 edges in flight
        int s0 = srcs[j];
        int s1 = srcs[j + 4];
        int s2 = srcs[j + 8];
        int s3 = srcs[j + 12];
        float d0 = dis[s0], d1 = dis[s1], d2 = dis[s2], d3 = dis[s3];
        uint4 u0 = h4[(unsigned)s0 * 8u + m8];
        uint4 u1 = h4[(unsigned)s1 * 8u + m8];
        uint4 u2 = h4[(unsigned)s2 * 8u + m8];
        uint4 u3 = h4[(unsigned)s3 * 8u + m8];
        ACC(u0, d0); ACC(u1, d1); ACC(u2, d2); ACC(u3, d3);
    }
    for (; j + 4 < end; j += 8) {               // 2 edges in flight
        int s0 = srcs[j];
        int s1 = srcs[j + 4];
        float d0 = dis[s0], d1 = dis[s1];
        uint4 u0 = h4[(unsigned)s0 * 8u + m8];
        uint4 u1 = h4[(unsigned)s1 * 8u + m8];
        ACC(u0, d0); ACC(u1, d1);
    }
    if (j < end) {
        int s0 = srcs[j];
        float d0 = dis[s0];
        uint4 u0 = h4[(unsigned)s0 * 8u + m8];
        ACC(u0, d0);
    }
#undef ACC

#pragma unroll
    for (int off = 8; off < 32; off <<= 1) {
        a0 += __shfl_xor(a0, off); a1 += __shfl_xor(a1, off);
        a2 += __shfl_xor(a2, off); a3 += __shfl_xor(a3, off);
        a4 += __shfl_xor(a4, off); a5 += __shfl_xor(a5, off);
        a6 += __shfl_xor(a6, off); a7 += __shfl_xor(a7, off);
    }
    float4 ba = ((const float4*)b1)[m8 * 2];
    float4 bb = ((const float4*)b1)[m8 * 2 + 1];
    float4 wa = ((const float4*)W2)[m8 * 2];
    float4 wb = ((const float4*)W2)[m8 * 2 + 1];
    float v = fmaxf(fmaf(dd, a0, ba.x), 0.f) * wa.x + fmaxf(fmaf(dd, a1, ba.y), 0.f) * wa.y
            + fmaxf(fmaf(dd, a2, ba.z), 0.f) * wa.z + fmaxf(fmaf(dd, a3, ba.w), 0.f) * wa.w
            + fmaxf(fmaf(dd, a4, bb.x), 0.f) * wb.x + fmaxf(fmaf(dd, a5, bb.y), 0.f) * wb.y
            + fmaxf(fmaf(dd, a6, bb.z), 0.f) * wb.z + fmaxf(fmaf(dd, a7, bb.w), 0.f) * wb.w;
#pragma unroll
    for (int off = 1; off < 8; off <<= 1) v += __shfl_xor(v, off);
    if ((lane & 31) == 0) zd[i] = v * dd;
}

// ================= agg2 (2 nodes/wave) + fused padded output =================
__global__ __launch_bounds__(256) void k_gather2(const int* __restrict__ srcs,
                                                 const int* __restrict__ row_start,
                                                 const int* __restrict__ row_end,
                                                 const float* __restrict__ dis,
                                                 const float* __restrict__ zd,
                                                 const float* __restrict__ b2,
                                                 float* __restrict__ out, int n) {
    int i = blockIdx.x * 8 + (threadIdx.x >> 5);
    int l = threadIdx.x & 31;
    float acc = 0.f;
    int beg = row_start[i], end = row_end[i];
    for (int j = beg + l; j < end; j += 32)
        acc += zd[srcs[j]];
#pragma unroll
    for (int off = 1; off < 32; off <<= 1) acc += __shfl_xor(acc, off);
    float y = (acc + zd[i]) * dis[i] + b2[0];
    float4 v = make_float4(0.f, 0.f, 0.f, 0.f);
    if (l == 0) v.x = y;
    ((float4*)out)[(size_t)i * 32 + l] = v;
}

extern "C" void kernel_launch(void* const* d_in, const int* in_sizes, int n_in,
                              void* d_out, int out_size, void* d_ws, size_t ws_size,
                              hipStream_t stream) {
    const float* x  = (const float*)d_in[0];
    const int*   ei = (const int*)d_in[1];   // [2, E] int32
    const float* W1 = (const float*)d_in[2];
    const float* b1 = (const float*)d_in[3];
    const float* W2 = (const float*)d_in[4];
    const float* b2 = (const float*)d_in[5];
    float* out = (float*)d_out;

    const int n = N_NODES;
    const int E = N_EDGES;
    const int* src = ei;
    const int* dst = ei + E;

    // ws: deg[n] | cursor[n] | srcs_sorted int[NB*BKT_CAP] (8MB) | row_start[n] |
    //     row_end[n] | dis f[n] | h1s ushort[n*64] (12.8MB) | zd f[n]
    int* deg         = (int*)d_ws;
    int* cursor      = deg + n;
    int* srcs_sorted = cursor + n;
    int* row_start   = srcs_sorted + (size_t)NB * BKT_CAP;
    int* row_end     = row_start + n;
    float* dis       = (float*)(row_end + n);
    unsigned short* h1s = (unsigned short*)(dis + n);
    float* zd        = (float*)(h1s + (size_t)n * D_HID);

    hipMemsetAsync(deg, 0, n * sizeof(int), stream);
    k_fused<<<HIST_NB + GEMM_NB, FST, 0, stream>>>(dst, deg, E, x, W1, h1s, n);
    k_rows<<<NB, 256, 0, stream>>>(deg, row_start, row_end, cursor, dis, n);
    k_scatter<<<1568, 256, 0, stream>>>(src, dst, cursor, srcs_sorted, E);
    k_gather1<<<(n + 7) / 8, 256, 0, stream>>>(srcs_sorted, row_start, row_end, dis,
                                               (const uint4*)h1s, b1, W2, zd, n);
    k_gather2<<<(n + 7) / 8, 256, 0, stream>>>(srcs_sorted, row_start, row_end, dis,
                                               zd, b2, out, n);
}

// Round 11
// 176.848 us; speedup vs baseline: 1.9714x; 1.9714x over previous
//
#include <hip/hip_runtime.h>

#define N_NODES 100000
#define N_EDGES 1600000
#define D_IN 128
#define D_HID 64

#define BKT_SHIFT 8
#define BKT_NODES 256
#define NB 391          // ceil(N_NODES / 256) buckets
#define NBLK 392        // scatter blocks
#define SLOT 32         // slots per (bucket,block)
#define SEG4 (SLOT / 4)
#define REG4 (NBLK * SEG4)   // uint4s per bucket region = 3136
#define BKT_CAP 5120
#define OVF_CAP 8192

#define FST 512         // fused kernel block size
#define BST 1024        // bsort block size
#define GEMM_NB 782     // gemm-role blocks (2 tiles of 64 nodes each)

typedef __attribute__((ext_vector_type(8))) short bf16x8;
typedef __attribute__((ext_vector_type(4))) float f32x4;

__device__ __forceinline__ unsigned short f2b(float f) {
    union { float f; unsigned u; } c; c.f = f;
    unsigned r = (c.u + 0x7FFFu + ((c.u >> 16) & 1u)) >> 16;   // RNE
    return (unsigned short)r;
}
__device__ __forceinline__ float blo(unsigned u) { return __uint_as_float(u << 16); }
__device__ __forceinline__ float bhi(unsigned u) { return __uint_as_float(u & 0xffff0000u); }

// ===== fused: blocks [0,392) = edge partition; blocks [392,1174) = layer-1 GEMM =====
// GEMM writes h1 rows as per-row-scaled INT8 (64B = 1 cache line per row); the scale
// is folded into dq[node] = dis[node]*scale[node] later (bsort epilogue), so the
// gather inner loop cost is unchanged. No escatter<->gemm dependency.
#define LS 136
__global__ __launch_bounds__(FST) void k_fused(const int* __restrict__ src,
                                               const int* __restrict__ dst,
                                               int* __restrict__ pairs,
                                               int* __restrict__ cnt_blk,
                                               int* __restrict__ ovf_cnt,
                                               int2* __restrict__ ovf, int E,
                                               const float* __restrict__ x,
                                               const float* __restrict__ W1,
                                               unsigned char* __restrict__ h1s8,
                                               float* __restrict__ scale, int n) {
    __shared__ __align__(16) unsigned char smem[52224];
    int tid = threadIdx.x;

    if (blockIdx.x < NBLK) {
        // ---------------- escatter role (proven round-7/9 body) ----------------
        int* lp   = (int*)smem;            // NB*SLOT ints
        int* lcur = lp + NB * SLOT;        // NB ints
        for (int t = tid; t < NB; t += FST) lcur[t] = 0;
        __syncthreads();
        int chunk = (E + NBLK - 1) / NBLK;
        int beg = blockIdx.x * chunk;
        int end = min(beg + chunk, E);
        for (int e = beg + tid; e < end; e += FST) {
            int d = dst[e], s = src[e];
            int bk = d >> BKT_SHIFT;
            int slot = atomicAdd(&lcur[bk], 1);
            if (slot < SLOT)
                lp[(bk << 5) + slot] = (s << BKT_SHIFT) | (d & (BKT_NODES - 1));
            else {
                int o = atomicAdd(ovf_cnt, 1);
                if (o < OVF_CAP) ovf[o] = make_int2(s, d);
            }
        }
        __syncthreads();
        uint4* p4 = (uint4*)pairs;
        const uint4* lp4 = (const uint4*)lp;
        for (int i4 = tid; i4 < NB * SEG4; i4 += FST) {
            int bk = i4 >> 3;
            int c = min(lcur[bk], SLOT);
            if (((i4 & 7) << 2) < c)
                p4[((size_t)bk * NBLK + blockIdx.x) * SEG4 + (i4 & 7)] = lp4[i4];
        }
        for (int t = tid; t < NB; t += FST)
            cnt_blk[t * NBLK + blockIdx.x] = min(lcur[t], SLOT);
    } else {
        // ---------------- GEMM role: 2 independent 64-node tiles ----------------
        unsigned short* ws = (unsigned short*)smem;        // [64][LS] shared W1^T
        unsigned short* xs = ws + 64 * LS;                 // 2 x [64][LS]
        int half = tid >> 8;          // 0/1 (waves 0-3 / 4-7)
        int t2 = tid & 255;
        int node0 = (blockIdx.x - NBLK) * 128 + half * 64;
        unsigned short* xsh = xs + half * 64 * LS;

        // W1 [128][64] fp32 (L2-hot) -> ws[f][k] bf16, cooperative across 512 thr
#pragma unroll
        for (int it = 0; it < 16; ++it) {
            int e = tid + it * 512;
            int k = e >> 6, f = e & 63;
            ws[f * LS + k] = f2b(W1[e]);
        }
#pragma unroll
        for (int it = 0; it < 8; ++it) {
            int e4 = t2 + it * 256;
            int node = e4 >> 5;
            int k = (e4 & 31) * 4;
            float4 v = make_float4(0.f, 0.f, 0.f, 0.f);
            if (node0 + node < n)
                v = ((const float4*)x)[((size_t)(node0 + node) * D_IN + k) >> 2];
            uint2 u;
            u.x = (unsigned)f2b(v.x) | ((unsigned)f2b(v.y) << 16);
            u.y = (unsigned)f2b(v.z) | ((unsigned)f2b(v.w) << 16);
            *(uint2*)&xsh[node * LS + k] = u;
        }
        __syncthreads();

        int wv = t2 >> 6;
        int lane = t2 & 63;
        int m16 = lane & 15;
        int q = lane >> 4;

        bf16x8 afrag[4];
#pragma unroll
        for (int ks = 0; ks < 4; ++ks)
            afrag[ks] = *(const bf16x8*)&xsh[(wv * 16 + m16) * LS + ks * 32 + q * 8];

        f32x4 acc[4];
#pragma unroll
        for (int ft = 0; ft < 4; ++ft) acc[ft] = (f32x4){0.f, 0.f, 0.f, 0.f};

#pragma unroll
        for (int ft = 0; ft < 4; ++ft)
#pragma unroll
            for (int ks = 0; ks < 4; ++ks) {
                bf16x8 bfrag = *(const bf16x8*)&ws[(ft * 16 + m16) * LS + ks * 32 + q * 8];
                acc[ft] = __builtin_amdgcn_mfma_f32_16x16x32_bf16(afrag[ks], bfrag, acc[ft], 0, 0, 0);
            }

        // ---- int8 quantization epilogue: per-node max over 64 feats, pack, write ----
        char* hs8 = (char*)xsh;            // reuse this half's xs as 4KB staging
#pragma unroll
        for (int r = 0; r < 4; ++r) {
            int nl = wv * 16 + q * 4 + r;
            int node = node0 + nl;
            float mv = fmaxf(fmaxf(fabsf(acc[0][r]), fabsf(acc[1][r])),
                             fmaxf(fabsf(acc[2][r]), fabsf(acc[3][r])));
#pragma unroll
            for (int off = 1; off < 16; off <<= 1) mv = fmaxf(mv, __shfl_xor(mv, off));
            float inv = (mv > 0.f) ? 127.0f / mv : 0.f;
            if (m16 == 0 && node < n) scale[node] = mv * (1.0f / 127.0f);
#pragma unroll
            for (int ft = 0; ft < 4; ++ft) {
                int qi = __float2int_rn(acc[ft][r] * inv);
                qi = max(-127, min(127, qi));
                hs8[nl * 64 + ft * 16 + m16] = (char)qi;
            }
        }
        __syncthreads();
        // coalesced write: 64 rows x 64B per half = 256 uint4s
        const uint4* hs4 = (const uint4*)hs8;
        uint4* h84 = (uint4*)h1s8;
        {
            int nl = t2 >> 2;
            int node = node0 + nl;
            if (node < n) h84[(size_t)node * 4 + (t2 & 3)] = hs4[t2];
        }
    }
}

// ===== per-bucket sort (proven): staged region, 2 LDS passes; epilogue adds dq =====
__global__ __launch_bounds__(BST) void k_bsort(const uint4* __restrict__ pairs4,
                                               const int* __restrict__ cnt_blk,
                                               const int* __restrict__ ovf_cnt,
                                               const int2* __restrict__ ovf,
                                               const float* __restrict__ scale,
                                               int* __restrict__ srcs_sorted,
                                               int* __restrict__ row_start,
                                               int* __restrict__ row_end,
                                               float* __restrict__ dis,
                                               float* __restrict__ dq, int n) {
    __shared__ uint4 reg4[REG4];      // 50,176 B staged region
    __shared__ int segc[NBLK];
    __shared__ int cnt[BKT_NODES];
    __shared__ int exc[BKT_NODES];
    __shared__ int sorted[BKT_CAP];   // 20,480 B
    __shared__ int nE_sh;
    int b = blockIdx.x;
    int tid = threadIdx.x;
    int node0 = b << BKT_SHIFT;
    int ocnt = min(ovf_cnt[0], OVF_CAP);
    const uint4* region = pairs4 + (size_t)b * REG4;

    for (int i = tid; i < NBLK; i += BST) segc[i] = cnt_blk[b * NBLK + i];
    if (tid < BKT_NODES) cnt[tid] = 0;
    __syncthreads();

    // fused stage + histogram; load only uint4s that hold valid slots
    for (int i4 = tid; i4 < REG4; i4 += BST) {
        int c = segc[i4 >> 3];
        int k = (i4 & 7) * 4;
        if (k < c) {
            uint4 v = region[i4];
            reg4[i4] = v;
            atomicAdd(&cnt[v.x & (BKT_NODES - 1)], 1);
            if (k + 1 < c) atomicAdd(&cnt[v.y & (BKT_NODES - 1)], 1);
            if (k + 2 < c) atomicAdd(&cnt[v.z & (BKT_NODES - 1)], 1);
            if (k + 3 < c) atomicAdd(&cnt[v.w & (BKT_NODES - 1)], 1);
        }
    }
    for (int k = tid; k < ocnt; k += BST) {
        int2 e = ovf[k];
        if ((e.y >> BKT_SHIFT) == b) atomicAdd(&cnt[e.y & (BKT_NODES - 1)], 1);
    }
    __syncthreads();

    if (tid < 64) {   // wave-0 exclusive scan of cnt[256]
        int run = 0;
        for (int c = 0; c < BKT_NODES; c += 64) {
            int v = cnt[c + tid];
            int inc = v;
            for (int off = 1; off < 64; off <<= 1) {
                int t2 = __shfl_up(inc, off);
                if (tid >= off) inc += t2;
            }
            exc[c + tid] = run + inc - v;
            run += __shfl(inc, 63);
        }
        if (tid == 63) nE_sh = run;
    }
    __syncthreads();

    if (tid < BKT_NODES) {
        int node = node0 + tid;
        if (node < n) {
            int rs = b * BKT_CAP + exc[tid];
            row_start[node] = rs;
            row_end[node] = rs + cnt[tid];
            float dv = rsqrtf((float)cnt[tid] + 1.0f);
            dis[node] = dv;
            dq[node] = dv * scale[node];     // fold int8 row scale into edge weight
        }
    }
    int nE = nE_sh;
    __syncthreads();
    if (tid < BKT_NODES) cnt[tid] = exc[tid];   // repurpose as per-node cursor
    __syncthreads();

    // pass 2: place (LDS reads)
    for (int i4 = tid; i4 < REG4; i4 += BST) {
        int c = segc[i4 >> 3];
        int k = (i4 & 7) * 4;
        if (k < c) {
            uint4 v = reg4[i4];
            { int p = atomicAdd(&cnt[v.x & (BKT_NODES - 1)], 1); sorted[p] = (int)(v.x >> 8); }
            if (k + 1 < c) { int p = atomicAdd(&cnt[v.y & (BKT_NODES - 1)], 1); sorted[p] = (int)(v.y >> 8); }
            if (k + 2 < c) { int p = atomicAdd(&cnt[v.z & (BKT_NODES - 1)], 1); sorted[p] = (int)(v.z >> 8); }
            if (k + 3 < c) { int p = atomicAdd(&cnt[v.w & (BKT_NODES - 1)], 1); sorted[p] = (int)(v.w >> 8); }
        }
    }
    for (int k = tid; k < ocnt; k += BST) {
        int2 e = ovf[k];
        if ((e.y >> BKT_SHIFT) == b) {
            int p = atomicAdd(&cnt[e.y & (BKT_NODES - 1)], 1);
            sorted[p] = e.x;
        }
    }
    __syncthreads();

    // coalesced write-out
    int gbase = b * BKT_CAP;
    for (int k = tid; k < nE; k += BST)
        srcs_sorted[gbase + k] = sorted[k];
}

// ======= fused agg1 + bias + ReLU + dot(W2) -> zd = z*dis; INT8 64B rows ===========
// Half-wave per node, 4 edge groups x 8 feat lanes; 4-deep batching; per-edge weight
// dq[src] = dis*scale. One cache line per edge row (halves line misses vs bf16).
__global__ __launch_bounds__(256) void k_gather1(const int* __restrict__ srcs,
                                                 const int* __restrict__ row_start,
                                                 const int* __restrict__ row_end,
                                                 const float* __restrict__ dis,
                                                 const float* __restrict__ dq,
                                                 const uint2* __restrict__ h2,
                                                 const float* __restrict__ b1,
                                                 const float* __restrict__ W2,
                                                 float* __restrict__ zd, int n) {
    int i = blockIdx.x * 8 + (threadIdx.x >> 5);     // node for this half-wave
    int lane = threadIdx.x & 63;
    int g = (lane >> 3) & 3;  // edge group within half-wave
    int m8 = lane & 7;        // feature block (feats 8*m8 .. 8*m8+7)
    float dd = dis[i];

    float a0, a1, a2, a3, a4, a5, a6, a7;
    {   // self-loop handled by group 0: weight dq[i]
        uint2 u = h2[(unsigned)i * 8u + m8];
        float w = (g == 0) ? dq[i] : 0.f;
        a0 = w * (float)((int)(u.x << 24) >> 24);
        a1 = w * (float)((int)(u.x << 16) >> 24);
        a2 = w * (float)((int)(u.x << 8) >> 24);
        a3 = w * (float)((int)u.x >> 24);
        a4 = w * (float)((int)(u.y << 24) >> 24);
        a5 = w * (float)((int)(u.y << 16) >> 24);
        a6 = w * (float)((int)(u.y << 8) >> 24);
        a7 = w * (float)((int)u.y >> 24);
    }

#define ACC8(u, ds) { \
    a0 = fmaf(ds, (float)((int)(u.x << 24) >> 24), a0); \
    a1 = fmaf(ds, (float)((int)(u.x << 16) >> 24), a1); \
    a2 = fmaf(ds, (float)((int)(u.x << 8) >> 24), a2);  \
    a3 = fmaf(ds, (float)((int)u.x >> 24), a3);         \
    a4 = fmaf(ds, (float)((int)(u.y << 24) >> 24), a4); \
    a5 = fmaf(ds, (float)((int)(u.y << 16) >> 24), a5); \
    a6 = fmaf(ds, (float)((int)(u.y << 8) >> 24), a6);  \
    a7 = fmaf(ds, (float)((int)u.y >> 24), a7); }
    int end = row_end[i];
    int j = row_start[i] + g;
    for (; j + 12 < end; j += 16) {             // 4 edges in flight
        int s0 = srcs[j];
        int s1 = srcs[j + 4];
        int s2 = srcs[j + 8];
        int s3 = srcs[j + 12];
        float d0 = dq[s0], d1 = dq[s1], d2 = dq[s2], d3 = dq[s3];
        uint2 u0 = h2[(unsigned)s0 * 8u + m8];
        uint2 u1 = h2[(unsigned)s1 * 8u + m8];
        uint2 u2 = h2[(unsigned)s2 * 8u + m8];
        uint2 u3 = h2[(unsigned)s3 * 8u + m8];
        ACC8(u0, d0); ACC8(u1, d1); ACC8(u2, d2); ACC8(u3, d3);
    }
    for (; j + 4 < end; j += 8) {               // 2 edges in flight
        int s0 = srcs[j];
        int s1 = srcs[j + 4];
        float d0 = dq[s0], d1 = dq[s1];
        uint2 u0 = h2[(unsigned)s0 * 8u + m8];
        uint2 u1 = h2[(unsigned)s1 * 8u + m8];
        ACC8(u0, d0); ACC8(u1, d1);
    }
    if (j < end) {
        int s0 = srcs[j];
        float d0 = dq[s0];
        uint2 u0 = h2[(unsigned)s0 * 8u + m8];
        ACC8(u0, d0);
    }
#undef ACC8

#pragma unroll
    for (int off = 8; off < 32; off <<= 1) {
        a0 += __shfl_xor(a0, off); a1 += __shfl_xor(a1, off);
        a2 += __shfl_xor(a2, off); a3 += __shfl_xor(a3, off);
        a4 += __shfl_xor(a4, off); a5 += __shfl_xor(a5, off);
        a6 += __shfl_xor(a6, off); a7 += __shfl_xor(a7, off);
    }
    float4 ba = ((const float4*)b1)[m8 * 2];
    float4 bb = ((const float4*)b1)[m8 * 2 + 1];
    float4 wa = ((const float4*)W2)[m8 * 2];
    float4 wb = ((const float4*)W2)[m8 * 2 + 1];
    float v = fmaxf(fmaf(dd, a0, ba.x), 0.f) * wa.x + fmaxf(fmaf(dd, a1, ba.y), 0.f) * wa.y
            + fmaxf(fmaf(dd, a2, ba.z), 0.f) * wa.z + fmaxf(fmaf(dd, a3, ba.w), 0.f) * wa.w
            + fmaxf(fmaf(dd, a4, bb.x), 0.f) * wb.x + fmaxf(fmaf(dd, a5, bb.y), 0.f) * wb.y
            + fmaxf(fmaf(dd, a6, bb.z), 0.f) * wb.z + fmaxf(fmaf(dd, a7, bb.w), 0.f) * wb.w;
#pragma unroll
    for (int off = 1; off < 8; off <<= 1) v += __shfl_xor(v, off);
    if ((lane & 31) == 0) zd[i] = v * dd;
}

// ================= agg2 (2 nodes/wave) + fused padded output =================
__global__ __launch_bounds__(256) void k_gather2(const int* __restrict__ srcs,
                                                 const int* __restrict__ row_start,
                                                 const int* __restrict__ row_end,
                                                 const float* __restrict__ dis,
                                                 const float* __restrict__ zd,
                                                 const float* __restrict__ b2,
                                                 float* __restrict__ out, int n) {
    int i = blockIdx.x * 8 + (threadIdx.x >> 5);
    int l = threadIdx.x & 31;
    float acc = 0.f;
    int beg = row_start[i], end = row_end[i];
    for (int j = beg + l; j < end; j += 32)
        acc += zd[srcs[j]];
#pragma unroll
    for (int off = 1; off < 32; off <<= 1) acc += __shfl_xor(acc, off);
    float y = (acc + zd[i]) * dis[i] + b2[0];
    float4 v = make_float4(0.f, 0.f, 0.f, 0.f);
    if (l == 0) v.x = y;
    ((float4*)out)[(size_t)i * 32 + l] = v;
}

extern "C" void kernel_launch(void* const* d_in, const int* in_sizes, int n_in,
                              void* d_out, int out_size, void* d_ws, size_t ws_size,
                              hipStream_t stream) {
    const float* x  = (const float*)d_in[0];
    const int*   ei = (const int*)d_in[1];   // [2, E] int32
    const float* W1 = (const float*)d_in[2];
    const float* b1 = (const float*)d_in[3];
    const float* W2 = (const float*)d_in[4];
    const float* b2 = (const float*)d_in[5];
    float* out = (float*)d_out;

    const int n = N_NODES;
    const int E = N_EDGES;
    const int* src = ei;
    const int* dst = ei + E;

    // ws: h1s8 u8[n*64] (6.4MB, 64B rows) | pairs int[NB*NBLK*SLOT] (19.6MB) |
    //     cnt_blk int[NB*NBLK] | srcs_sorted int[NB*BKT_CAP] (8MB) | row_start[n] |
    //     row_end[n] | ovf_cnt[4] | ovf int2[OVF_CAP] | dis f[n] | scale f[n] |
    //     dq f[n] | zd f[n]
    unsigned char* h1s8 = (unsigned char*)d_ws;
    int* pairs       = (int*)(h1s8 + (size_t)n * D_HID);
    int* cnt_blk     = pairs + (size_t)NB * NBLK * SLOT;
    int* srcs_sorted = cnt_blk + (size_t)NB * NBLK;
    int* row_start   = srcs_sorted + (size_t)NB * BKT_CAP;
    int* row_end     = row_start + n;
    int* ovf_cnt     = row_end + n;
    int2* ovf        = (int2*)(ovf_cnt + 4);
    float* dis       = (float*)(ovf + OVF_CAP);
    float* scale     = dis + n;
    float* dq        = scale + n;
    float* zd        = dq + n;

    hipMemsetAsync(ovf_cnt, 0, sizeof(int), stream);
    k_fused<<<NBLK + GEMM_NB, FST, 0, stream>>>(src, dst, pairs, cnt_blk, ovf_cnt,
                                                ovf, E, x, W1, h1s8, scale, n);
    k_bsort<<<NB, BST, 0, stream>>>((const uint4*)pairs, cnt_blk, ovf_cnt, ovf, scale,
                                    srcs_sorted, row_start, row_end, dis, dq, n);
    k_gather1<<<(n + 7) / 8, 256, 0, stream>>>(srcs_sorted, row_start, row_end, dis, dq,
                                               (const uint2*)h1s8, b1, W2, zd, n);
    k_gather2<<<(n + 7) / 8, 256, 0, stream>>>(srcs_sorted, row_start, row_end, dis,
                                               zd, b2, out, n);
}